// Round 5
// baseline (114.225 us; speedup 1.0000x reference)
//
#include <hip/hip_runtime.h>
#include <hip/hip_cooperative_groups.h>

namespace cg = cooperative_groups;

#define D 128          // D_IN == EMBED == 128
#define NROWS 8192     // N_FIRMS
#define NBLK 256       // one block per CU -> cooperative co-residency guaranteed
#define ROWS_PER_BLK (NROWS / NBLK)   // 32

// Single cooperative kernel:
//  A: a = Wv^T hw                       (per block, threads 0..127)
//  B: y = X a ; part[blk] = X_blk^T y   (32 rows/block; X slice kept in regs)
//  -- grid.sync() --
//  C: b = colsum(part) (split over 256 thr); c = Wk b ; w = Wq^T c
//  D: preds = X w + head_b              (reuses X from registers, no reload)
__global__ __launch_bounds__(256) void fused_all(const float* __restrict__ X,
                                                 const float* __restrict__ Wv,
                                                 const float* __restrict__ head_w,
                                                 const float* __restrict__ Wk,
                                                 const float* __restrict__ Wq,
                                                 const float* __restrict__ head_b,
                                                 float* __restrict__ part,
                                                 float* __restrict__ out) {
    __shared__ float a_s[D];
    __shared__ float red[4][D];
    __shared__ float red2[2][D];
    __shared__ float bs[D];
    __shared__ float cs[D];
    __shared__ float w_s[D];
    const int t = threadIdx.x;

    // ---- A: a[d] = sum_e Wv[e,d] * hw[e] ----
    if (t < D) {
        float s0 = 0.f, s1 = 0.f, s2 = 0.f, s3 = 0.f;
#pragma unroll
        for (int e = 0; e < D; e += 4) {
            s0 += Wv[(e + 0) * D + t] * head_w[e + 0];
            s1 += Wv[(e + 1) * D + t] * head_w[e + 1];
            s2 += Wv[(e + 2) * D + t] * head_w[e + 2];
            s3 += Wv[(e + 3) * D + t] * head_w[e + 3];
        }
        a_s[t] = (s0 + s1) + (s2 + s3);
    }
    __syncthreads();

    // ---- B: stream 32 rows, outer-product partial; stash X in registers ----
    const int lane = t & 63;
    const int wave = t >> 6;
    const int half = lane >> 5;
    const int l32  = lane & 31;
    const int col  = l32 * 4;
    const float4 a4 = *reinterpret_cast<const float4*>(a_s + col);
    const int rowBase = blockIdx.x * ROWS_PER_BLK + wave * 8 + half;
    float4 xs[4];
    float4 b4 = make_float4(0.f, 0.f, 0.f, 0.f);
#pragma unroll
    for (int it = 0; it < 4; ++it) {
        const int row = rowBase + it * 2;
        const float4 x4 = *reinterpret_cast<const float4*>(X + row * D + col);
        xs[it] = x4;
        float p = x4.x * a4.x + x4.y * a4.y + x4.z * a4.z + x4.w * a4.w;
#pragma unroll
        for (int m = 1; m <= 16; m <<= 1) p += __shfl_xor(p, m, 64);
        // p == y[row] across the 32-lane half
        b4.x += x4.x * p; b4.y += x4.y * p; b4.z += x4.z * p; b4.w += x4.w * p;
    }
    b4.x += __shfl_xor(b4.x, 32, 64);
    b4.y += __shfl_xor(b4.y, 32, 64);
    b4.z += __shfl_xor(b4.z, 32, 64);
    b4.w += __shfl_xor(b4.w, 32, 64);
    if (half == 0) *reinterpret_cast<float4*>(&red[wave][col]) = b4;
    __syncthreads();
    if (t < D)
        part[blockIdx.x * D + t] = (red[0][t] + red[1][t]) + (red[2][t] + red[3][t]);

    // ---- grid-wide barrier (device-scope visibility of part) ----
    cg::this_grid().sync();

    // ---- C: b = colsum(part), k-range split across the two thread halves ----
    {
        const int d  = t & (D - 1);          // 0..127
        const int k0 = (t >> 7) * (NBLK / 2); // 0 or 128
        float s0 = 0.f, s1 = 0.f, s2 = 0.f, s3 = 0.f;
#pragma unroll 8
        for (int k = 0; k < NBLK / 2; k += 4) {
            s0 += part[(k0 + k + 0) * D + d];
            s1 += part[(k0 + k + 1) * D + d];
            s2 += part[(k0 + k + 2) * D + d];
            s3 += part[(k0 + k + 3) * D + d];
        }
        red2[t >> 7][d] = (s0 + s1) + (s2 + s3);
    }
    __syncthreads();
    if (t < D) bs[t] = red2[0][t] + red2[1][t];
    __syncthreads();
    // c = Wk b
    if (t < D) {
        float s0 = 0.f, s1 = 0.f, s2 = 0.f, s3 = 0.f;
#pragma unroll
        for (int d = 0; d < D; d += 4) {
            s0 += Wk[t * D + d + 0] * bs[d + 0];
            s1 += Wk[t * D + d + 1] * bs[d + 1];
            s2 += Wk[t * D + d + 2] * bs[d + 2];
            s3 += Wk[t * D + d + 3] * bs[d + 3];
        }
        cs[t] = (s0 + s1) + (s2 + s3);
    }
    __syncthreads();
    // w = Wq^T c
    if (t < D) {
        float s0 = 0.f, s1 = 0.f, s2 = 0.f, s3 = 0.f;
#pragma unroll
        for (int e = 0; e < D; e += 4) {
            s0 += Wq[(e + 0) * D + t] * cs[e + 0];
            s1 += Wq[(e + 1) * D + t] * cs[e + 1];
            s2 += Wq[(e + 2) * D + t] * cs[e + 2];
            s3 += Wq[(e + 3) * D + t] * cs[e + 3];
        }
        w_s[t] = (s0 + s1) + (s2 + s3);
    }
    __syncthreads();

    // ---- D: preds from the register-resident X slices ----
    const float4 w4 = *reinterpret_cast<const float4*>(w_s + col);
    const float hb = head_b[0];
#pragma unroll
    for (int it = 0; it < 4; ++it) {
        const int row = rowBase + it * 2;
        const float4 x4 = xs[it];
        float p = x4.x * w4.x + x4.y * w4.y + x4.z * w4.z + x4.w * w4.w;
#pragma unroll
        for (int m = 1; m <= 16; m <<= 1) p += __shfl_xor(p, m, 64);
        if (l32 == 0) out[row] = p + hb;
    }
}

extern "C" void kernel_launch(void* const* d_in, const int* in_sizes, int n_in,
                              void* d_out, int out_size, void* d_ws, size_t ws_size,
                              hipStream_t stream) {
    const float* X      = (const float*)d_in[0];  // (8192,128)
    const float* Wq     = (const float*)d_in[1];  // (128,128)
    const float* Wk     = (const float*)d_in[2];  // (128,128)
    const float* Wv     = (const float*)d_in[3];  // (128,128)
    const float* head_w = (const float*)d_in[4];  // (1,128)
    const float* head_b = (const float*)d_in[5];  // (1,)
    float* out = (float*)d_out;                   // (8192,) f32
    float* part = (float*)d_ws;                   // 256*128 f32 = 128 KB

    void* args[] = {(void*)&X, (void*)&Wv, (void*)&head_w, (void*)&Wk,
                    (void*)&Wq, (void*)&head_b, (void*)&part, (void*)&out};
    hipLaunchCooperativeKernel((void*)fused_all, dim3(NBLK), dim3(256),
                               args, 0, stream);
}

// Round 6
// 75.454 us; speedup vs baseline: 1.5138x; 1.5138x over previous
//
#include <hip/hip_runtime.h>

#define D 128          // D_IN == EMBED == 128
#define NROWS 8192     // N_FIRMS
#define NBLK 256       // one block per CU
#define ROWS_PER_BLK (NROWS / NBLK)   // 32

// K2: a = Wv^T hw (wave-parallel, float4) ; y = X a ; part[blk] = X_blk^T y.
__global__ __launch_bounds__(256) void k2_xa_xty(const float* __restrict__ X,
                                                 const float* __restrict__ Wv,
                                                 const float* __restrict__ head_w,
                                                 float* __restrict__ part) {
    __shared__ float red[4][D];
    __shared__ float a_s[D];
    const int t = threadIdx.x;
    const int lane = t & 63;
    const int wave = t >> 6;
    const int half = lane >> 5;
    const int l32  = lane & 31;
    const int col  = l32 * 4;

    // ---- phase A: a[d] = sum_e Wv[e,d]*hw[e]; wave w owns e in [32w,32w+32),
    //      2 e's per iter (half), float4 across d. 16 coalesced loads/thread.
    {
        float4 acc = make_float4(0.f, 0.f, 0.f, 0.f);
#pragma unroll
        for (int i = 0; i < 16; ++i) {
            const int e = wave * 32 + i * 2 + half;
            const float4 v = *reinterpret_cast<const float4*>(Wv + e * D + col);
            const float h = head_w[e];
            acc.x += v.x * h; acc.y += v.y * h; acc.z += v.z * h; acc.w += v.w * h;
        }
        acc.x += __shfl_xor(acc.x, 32, 64);
        acc.y += __shfl_xor(acc.y, 32, 64);
        acc.z += __shfl_xor(acc.z, 32, 64);
        acc.w += __shfl_xor(acc.w, 32, 64);
        if (half == 0) *reinterpret_cast<float4*>(&red[wave][col]) = acc;
    }
    __syncthreads();
    if (t < D) a_s[t] = (red[0][t] + red[1][t]) + (red[2][t] + red[3][t]);
    __syncthreads();

    // ---- phase B: stream 32 rows, outer-product partial ----
    const float4 a4 = *reinterpret_cast<const float4*>(a_s + col);
    float4 b4 = make_float4(0.f, 0.f, 0.f, 0.f);
    const int rowBase = blockIdx.x * ROWS_PER_BLK + wave * 8 + half;
#pragma unroll
    for (int it = 0; it < 4; ++it) {
        const int row = rowBase + it * 2;
        const float4 x4 = *reinterpret_cast<const float4*>(X + row * D + col);
        float p = x4.x * a4.x + x4.y * a4.y + x4.z * a4.z + x4.w * a4.w;
#pragma unroll
        for (int m = 1; m <= 16; m <<= 1) p += __shfl_xor(p, m, 64);
        // p == y[row] across the 32-lane half
        b4.x += x4.x * p; b4.y += x4.y * p; b4.z += x4.z * p; b4.w += x4.w * p;
    }
    b4.x += __shfl_xor(b4.x, 32, 64);
    b4.y += __shfl_xor(b4.y, 32, 64);
    b4.z += __shfl_xor(b4.z, 32, 64);
    b4.w += __shfl_xor(b4.w, 32, 64);
    if (half == 0) *reinterpret_cast<float4*>(&red[wave][col]) = b4;
    __syncthreads();
    if (t < D)
        part[blockIdx.x * D + t] = (red[0][t] + red[1][t]) + (red[2][t] + red[3][t]);
}

// K3 (single block): b = colsum(part) ; c = Wk b ; w = Wq^T c.
__global__ __launch_bounds__(256) void k3_w(const float* __restrict__ part,
                                            const float* __restrict__ Wk,
                                            const float* __restrict__ Wq,
                                            float* __restrict__ w_out) {
    __shared__ float4 redp[8][32];
    __shared__ float bs[D];
    __shared__ float cs[D];
    __shared__ float red[4][D];
    const int t = threadIdx.x;

    // ---- b: 8-way k-split x 32 float4 col-groups, coalesced ----
    {
        const int ks = t >> 5;       // 0..7 -> k range [32ks, 32ks+32)
        const int g  = t & 31;       // float4 col group
        float4 s = make_float4(0.f, 0.f, 0.f, 0.f);
#pragma unroll 4
        for (int i = 0; i < 32; ++i) {
            const float4 v = *reinterpret_cast<const float4*>(part + (ks * 32 + i) * D + g * 4);
            s.x += v.x; s.y += v.y; s.z += v.z; s.w += v.w;
        }
        redp[ks][g] = s;
    }
    __syncthreads();
    if (t < 32) {
        float4 s = make_float4(0.f, 0.f, 0.f, 0.f);
#pragma unroll
        for (int j = 0; j < 8; ++j) {
            const float4 v = redp[j][t];
            s.x += v.x; s.y += v.y; s.z += v.z; s.w += v.w;
        }
        *reinterpret_cast<float4*>(bs + t * 4) = s;
    }
    __syncthreads();

    // ---- c = Wk b: row-dot, thread t streams its contiguous row ----
    if (t < D) {
        float4 s = make_float4(0.f, 0.f, 0.f, 0.f);
#pragma unroll 4
        for (int i = 0; i < 32; ++i) {
            const float4 wv = *reinterpret_cast<const float4*>(Wk + t * D + i * 4);
            const float4 bv = *reinterpret_cast<const float4*>(bs + i * 4);  // LDS broadcast
            s.x += wv.x * bv.x; s.y += wv.y * bv.y; s.z += wv.z * bv.z; s.w += wv.w * bv.w;
        }
        cs[t] = (s.x + s.y) + (s.z + s.w);
    }
    __syncthreads();

    // ---- w = Wq^T c: wave-split over e, float4 over d ----
    const int lane = t & 63;
    const int wave = t >> 6;
    const int half = lane >> 5;
    const int l32  = lane & 31;
    const int col  = l32 * 4;
    {
        float4 acc = make_float4(0.f, 0.f, 0.f, 0.f);
#pragma unroll
        for (int i = 0; i < 16; ++i) {
            const int e = wave * 32 + i * 2 + half;
            const float4 v = *reinterpret_cast<const float4*>(Wq + e * D + col);
            const float h = cs[e];
            acc.x += v.x * h; acc.y += v.y * h; acc.z += v.z * h; acc.w += v.w * h;
        }
        acc.x += __shfl_xor(acc.x, 32, 64);
        acc.y += __shfl_xor(acc.y, 32, 64);
        acc.z += __shfl_xor(acc.z, 32, 64);
        acc.w += __shfl_xor(acc.w, 32, 64);
        if (half == 0) *reinterpret_cast<float4*>(&red[wave][col]) = acc;
    }
    __syncthreads();
    if (t < D) w_out[t] = (red[0][t] + red[1][t]) + (red[2][t] + red[3][t]);
}

// K5: preds = X w + head_b — pure stream + butterfly.
__global__ __launch_bounds__(256) void k5_preds(const float* __restrict__ X,
                                                const float* __restrict__ w_vec,
                                                const float* __restrict__ head_b,
                                                float* __restrict__ out) {
    const int t = threadIdx.x;
    const int lane = t & 63;
    const int wave = t >> 6;
    const int half = lane >> 5;
    const int l32  = lane & 31;
    const int col  = l32 * 4;
    const float4 w4 = *reinterpret_cast<const float4*>(w_vec + col);
    const float hb = head_b[0];
    const int rowBase = blockIdx.x * ROWS_PER_BLK + wave * 8 + half;
#pragma unroll
    for (int it = 0; it < 4; ++it) {
        const int row = rowBase + it * 2;
        const float4 x4 = *reinterpret_cast<const float4*>(X + row * D + col);
        float p = x4.x * w4.x + x4.y * w4.y + x4.z * w4.z + x4.w * w4.w;
#pragma unroll
        for (int m = 1; m <= 16; m <<= 1) p += __shfl_xor(p, m, 64);
        if (l32 == 0) out[row] = p + hb;
    }
}

extern "C" void kernel_launch(void* const* d_in, const int* in_sizes, int n_in,
                              void* d_out, int out_size, void* d_ws, size_t ws_size,
                              hipStream_t stream) {
    const float* X      = (const float*)d_in[0];  // (8192,128)
    const float* Wq     = (const float*)d_in[1];  // (128,128)
    const float* Wk     = (const float*)d_in[2];  // (128,128)
    const float* Wv     = (const float*)d_in[3];  // (128,128)
    const float* head_w = (const float*)d_in[4];  // (1,128)
    const float* head_b = (const float*)d_in[5];  // (1,)
    float* out = (float*)d_out;                   // (8192,) f32

    float* part  = (float*)d_ws;                  // 256*128 f32 = 128 KB
    float* w_vec = (float*)d_ws + NBLK * D;       // 128 f32

    k2_xa_xty<<<NBLK, 256, 0, stream>>>(X, Wv, head_w, part);
    k3_w<<<1, 256, 0, stream>>>(part, Wk, Wq, w_vec);
    k5_preds<<<NBLK, 256, 0, stream>>>(X, w_vec, head_b, out);
}